// Round 4
// baseline (458.022 us; speedup 1.0000x reference)
//
#include <hip/hip_runtime.h>
#include <cstdint>
#include <cstddef>

#define GK0 0.7978845608028654f
#define GC1 0.044715f

typedef __attribute__((ext_vector_type(8))) short short8;
typedef __attribute__((ext_vector_type(4))) short short4v;
typedef __attribute__((ext_vector_type(4))) float floatx4;

__device__ __forceinline__ unsigned short f2bf(float f) {
  union { float f; unsigned int u; } v; v.f = f;
  unsigned int r = v.u + 0x7fffu + ((v.u >> 16) & 1u);   // RNE
  return (unsigned short)(r >> 16);
}

// ---- weights: [co][ci][3][3] f32 -> wt[khw][co][ci] bf16; also zero out ----
__global__ void k_wt(const float* __restrict__ w, unsigned short* __restrict__ wt,
                     float* __restrict__ out) {
  if (blockIdx.x == 0) {
    for (int i = threadIdx.x; i < 32 * 128; i += 256) out[i] = 0.0f;
  }
  int t = blockIdx.x * 256 + threadIdx.x;
  if (t >= 128 * 64 * 9) return;
  int co = t / 576; int r = t - co * 576; int ci = r / 9; int khw = r - ci * 9;
  wt[(khw * 128 + co) * 64 + ci] = f2bf(w[t]);
}

// ---- fused conv + bias + gelu + pool, h-sweep version ----
// grid (2 w-halves, 21 h-groups, 32 b), block 256 (4 waves)
// Each block sweeps 3 h-tiles (6 output rows = hbase..hbase+5), staging 8 input
// rows ONCE into an 8-slot LDS ring (76 KB). Rows for tile t+1 are prefetch-
// issued mid-K-loop of tile t (kk==8) so HBM latency hides behind ~9 MFMA iters.
__global__ __launch_bounds__(256, 2) void k_conv(
    const float* __restrict__ x, const unsigned short* __restrict__ wt,
    const float* __restrict__ bias, float* __restrict__ out) {
  __shared__ __align__(16) unsigned short xs[8 * 66 * 72];   // 8 row-slots
  const int tid = threadIdx.x;
  const int b = blockIdx.z, hbase = blockIdx.y * 6, w0 = blockIdx.x * 64;
  const int lane = tid & 63, wave = tid >> 6;
  const int wm = wave & 1, wn = wave >> 1;      // co-half, output-row-within-tile
  const int m = lane & 15, q = lane >> 4;

  const float* xb = x + (size_t)b * 64 * 16384;          // [ci][h][w]
  const int g = tid >> 4, w4 = tid & 15;                 // ci-group(4), w-group(4)
  const int hci = tid & 63, hrow = tid >> 6;             // halo mapping

  // ---- stage rows hbase..hbase+3 into slots 0..3 (wide, batched) ----
  {
    const float* p0 = xb + (size_t)(4 * g) * 16384 + (size_t)hbase * 128 + w0 + 4 * w4;
    float4 rv[16];
#pragma unroll
    for (int row = 0; row < 4; row++)
#pragma unroll
      for (int c = 0; c < 4; c++)
        rv[row * 4 + c] = *(const float4*)(p0 + (size_t)c * 16384 + row * 128);
    float2 hv = make_float2(0.f, 0.f);
    if (w0 == 0) hv = *(const float2*)(xb + (size_t)hci * 16384 + (size_t)(hbase + hrow) * 128 + 64);
#pragma unroll
    for (int row = 0; row < 4; row++) {
      unsigned short* dr = xs + row * (66 * 72);
#pragma unroll
      for (int wj = 0; wj < 4; wj++) {
        short4v sv;
#pragma unroll
        for (int c = 0; c < 4; c++) sv[c] = (short)f2bf(((const float*)&rv[row * 4 + c])[wj]);
        *(short4v*)(dr + (4 * w4 + wj) * 72 + 4 * g) = sv;   // pack 4 ci -> b64
      }
    }
    xs[hrow * (66 * 72) + 64 * 72 + hci] = f2bf(hv.x);
    xs[hrow * (66 * 72) + 65 * 72 + hci] = f2bf(hv.y);
  }
  __syncthreads();

  // bias fragment (hoisted; bias applies inside GELU each tile)
  float bvv[4][4];
#pragma unroll
  for (int mt = 0; mt < 4; mt++)
#pragma unroll
    for (int r2 = 0; r2 < 4; r2++) bvv[mt][r2] = bias[wm * 64 + mt * 16 + q * 4 + r2];

  const unsigned short* wbase = wt + ((wm * 64 + m) * 64 + q * 8);
  int bb[4];
#pragma unroll
  for (int nt = 0; nt < 4; nt++) bb[nt] = (nt * 16 + m) * 72 + q * 8;

  float gsum[4][4];
#pragma unroll
  for (int i = 0; i < 4; i++)
#pragma unroll
    for (int j = 0; j < 4; j++) gsum[i][j] = 0.f;

  for (int t = 0; t < 3; t++) {
    const bool pre = (t < 2);
    floatx4 acc[4][4];
#pragma unroll
    for (int i = 0; i < 4; i++)
#pragma unroll
      for (int j = 0; j < 4; j++) acc[i][j] = (floatx4){0.f, 0.f, 0.f, 0.f};

    short8 a_cur[4], a_nxt[4];
#pragma unroll
    for (int mt = 0; mt < 4; mt++) a_cur[mt] = *(const short8*)(wbase + mt * 1024);

    float4 pr[8];
    float2 ph = make_float2(0.f, 0.f);

#pragma unroll
    for (int kk = 0; kk < 18; kk++) {
      const int khw = kk >> 1, cb = (kk & 1) << 5;
      const int kh = khw / 3, kw = khw - kh * 3;
      if (kk < 17) {
        const int khw2 = (kk + 1) >> 1, cb2 = ((kk + 1) & 1) << 5;
        const unsigned short* p = wbase + khw2 * 8192 + cb2;
#pragma unroll
        for (int mt = 0; mt < 4; mt++) a_nxt[mt] = *(const short8*)(p + mt * 1024);
      }
      short8 bf[4];
      const int off = ((2 * t + wn + kh) * 66 + kw) * 72 + cb;
#pragma unroll
      for (int nt = 0; nt < 4; nt++) bf[nt] = *(const short8*)(&xs[bb[nt] + off]);
#pragma unroll
      for (int mt = 0; mt < 4; mt++)
#pragma unroll
        for (int nt = 0; nt < 4; nt++)
          acc[mt][nt] = __builtin_amdgcn_mfma_f32_16x16x32_bf16(a_cur[mt], bf[nt], acc[mt][nt], 0, 0, 0);
      if (kk == 8 && pre) {   // issue next 2 rows mid-K-loop: latency hides behind iters 9..17
        const int prow = hbase + 4 + 2 * t;
        const float* pp = xb + (size_t)(4 * g) * 16384 + (size_t)prow * 128 + w0 + 4 * w4;
#pragma unroll
        for (int rr = 0; rr < 2; rr++)
#pragma unroll
          for (int c = 0; c < 4; c++)
            pr[rr * 4 + c] = *(const float4*)(pp + (size_t)c * 16384 + rr * 128);
        if (w0 == 0 && tid < 128)
          ph = *(const float2*)(xb + (size_t)hci * 16384 + (size_t)(prow + (hrow & 1)) * 128 + 64);
      }
#pragma unroll
      for (int mt = 0; mt < 4; mt++) a_cur[mt] = a_nxt[mt];
    }

    // per-tile epilogue math (no atomics): bias + fast tanh-GELU + masked w-sum
#pragma unroll
    for (int mt = 0; mt < 4; mt++)
#pragma unroll
      for (int r2 = 0; r2 < 4; r2++) {
        float s = 0.f;
#pragma unroll
        for (int nt = 0; nt < 4; nt++) {
          float y = acc[mt][nt][r2] + bvv[mt][r2];
          float u = GK0 * (y + GC1 * y * y * y);
          float e = __expf(-2.0f * u);
          float gg = y * __builtin_amdgcn_rcpf(1.0f + e);    // == 0.5y(1+tanh u)
          if (w0 + nt * 16 + m < 126) s += gg;
        }
        gsum[mt][r2] += s;
      }

    if (pre) {   // convert + write prefetched rows into slots 4+2t, 5+2t
      const int s0 = 4 + 2 * t;
#pragma unroll
      for (int rr = 0; rr < 2; rr++) {
        unsigned short* dr = xs + (s0 + rr) * (66 * 72);
#pragma unroll
        for (int wj = 0; wj < 4; wj++) {
          short4v sv;
#pragma unroll
          for (int c = 0; c < 4; c++) sv[c] = (short)f2bf(((const float*)&pr[rr * 4 + c])[wj]);
          *(short4v*)(dr + (4 * w4 + wj) * 72 + 4 * g) = sv;
        }
      }
      if (tid < 128) {   // halo for the 2 new rows (zeros when w0==64)
        unsigned short* dr = xs + (s0 + (hrow & 1)) * (66 * 72);
        dr[64 * 72 + hci] = f2bf(ph.x);
        dr[65 * 72 + hci] = f2bf(ph.y);
      }
    }
    __syncthreads();
  }

  // final: reduce gsum over the 16 column-lanes, one atomic round per block
  const float inv_area = 1.0f / (126.0f * 126.0f);
  float* orow = out + b * 128;
#pragma unroll
  for (int mt = 0; mt < 4; mt++)
#pragma unroll
    for (int r2 = 0; r2 < 4; r2++) {
      float s = gsum[mt][r2];
#pragma unroll
      for (int d = 1; d < 16; d <<= 1) s += __shfl_xor(s, d, 64);
      if (m == 0) atomicAdd(&orow[wm * 64 + mt * 16 + q * 4 + r2], s * inv_area);
    }
}

extern "C" void kernel_launch(void* const* d_in, const int* in_sizes, int n_in,
                              void* d_out, int out_size, void* d_ws, size_t ws_size,
                              hipStream_t stream) {
  const float* x    = (const float*)d_in[0];
  const float* w    = (const float*)d_in[1];
  const float* bias = (const float*)d_in[2];
  float* out = (float*)d_out;

  unsigned short* wbuf = (unsigned short*)d_ws;   // 9*128*64 bf16 = 144 KiB
  if (ws_size < (size_t)9 * 128 * 64 * 2) return;

  k_wt<<<288, 256, 0, stream>>>(w, wbuf, out);
  k_conv<<<dim3(2, 21, 32), 256, 0, stream>>>(x, wbuf, bias, out);
}